// Round 10
// baseline (2363.007 us; speedup 1.0000x reference)
//
#include <hip/hip_runtime.h>
#include <hip/hip_bf16.h>
#include <math.h>

using bf16 = __hip_bfloat16;

typedef short s8v __attribute__((ext_vector_type(8)));   // 8 bf16 bit-pattern (4 VGPRs)
typedef float f4v __attribute__((ext_vector_type(4)));   // MFMA accumulator

// ---------------- problem dims ----------------
static constexpr int  BB  = 2048;
static constexpr int  IH  = 23, IW = 31;   // stage 1 spatial  (HW1 = 713)
static constexpr int  PH  = 11, PW = 15;   // after pool1      (HW2 = 165)
static constexpr int  QH  = 5,  QW = 7;    // after pool2      (HW3 = 35)
static constexpr int  HW1 = 713, HW2 = 165, HW3 = 35;
static constexpr long NSITE1 = (long)BB * HW1;   // 1,460,224
static constexpr long NSITE2 = (long)BB * HW2;   //   337,920
static constexpr long NSITE3 = (long)BB * HW3;   //    71,680

// ---------------- workspace layout ----------------
// floats [0..2048): BN stats (memset 8192 B each call)
static constexpr long OFF_S1 = 0,   OFF_Q1 = 64;
static constexpr long OFF_S2 = 128, OFF_Q2 = 192;
static constexpr long OFF_S3 = 256, OFF_Q3 = 320;
static constexpr long OFF_S4 = 384, OFF_Q4 = 512;
static constexpr long OFF_N1 = 640, OFF_N2 = 641;
static constexpr long OFF_SC1 = 704,  OFF_SH1 = 768;
static constexpr long OFF_SC2 = 832,  OFF_SH2 = 896;
static constexpr long OFF_SC3 = 960,  OFF_SH3 = 1024;
static constexpr long OFF_SC4 = 1088, OFF_SH4 = 1216;
// bf16 area begins at float offset 4096. Offsets below in bf16 elements:
static constexpr long MOFF_M0  = 0;                   // m0  b-major  (1,460,224)
static constexpr long MOFF_M0H = 1460224;             // m0h hw-major (1,460,224)
static constexpr long MOFF_M1H = 2920448;             // m1h hw-major (337,920)
static constexpr long MOFF_M2H = 3258368;             // m2h hw-major (71,680)
static constexpr long AOFF     = 3330048;             // region A (43,253,760)
static constexpr long BOFF     = AOFF + 43253760L;    // region B (46,727,168)
// region-internal stashes (bf16 elems):
static constexpr long A_XMT  = 24000000L;   // xmT uint view (2,920,448 bf16)
static constexpr long A_WB2  = 28000000L;   // [9][1][32][32]  = 9,216
static constexpr long A_WB3  = 28100000L;   // [9][1][64][32]  = 18,432
static constexpr long A_WBL  = 20000000L;   // [9][4][768][32] = 884,736
static constexpr long B_WB4  = 22000000L;   // [9][2][128][32] = 73,728
static constexpr long B_WFC1 = 23000000L;   // wfc1T8 [1120][1024][8] = 9,175,040

__device__ __forceinline__ float sigmoidf_(float x) { return 1.f / (1.f + __expf(-x)); }
__device__ __forceinline__ float b2f(bf16 v) { return __bfloat162float(v); }
__device__ __forceinline__ bf16  f2b(float v) { return __float2bfloat16(v); }

__device__ __forceinline__ void ld8(const bf16* p, float* f) {
    union { uint4 u; unsigned short s[8]; } cv;
    cv.u = *(const uint4*)p;
#pragma unroll
    for (int i = 0; i < 8; i++) f[i] = __uint_as_float(((unsigned int)cv.s[i]) << 16);
}
__device__ __forceinline__ void st8(bf16* p, const float* f) {
    union { uint4 u; bf16 h[8]; } cv;
#pragma unroll
    for (int i = 0; i < 8; i++) cv.h[i] = f2b(f[i]);
    *(uint4*)p = cv.u;
}

// ---------------- weight convert: W[tap][cin][cout] f32 -> wb[tap][kk][cout][32] bf16 (zero-pad) ----------------
__global__ void cvt_wsplit_k(const float* __restrict__ W, bf16* __restrict__ wb,
                             int CIN, int COUT, int KK, int total) {
    int idx = blockIdx.x * 256 + threadIdx.x;
    if (idx >= total) return;
    int kidx = idx & 31;
    int t2   = idx >> 5;
    int co   = t2 % COUT;
    int t3   = t2 / COUT;
    int kk   = t3 % KK;
    int tap  = t3 / KK;
    int cin  = kk * 32 + kidx;
    wb[idx] = (cin < CIN) ? f2b(W[((long)(tap * CIN + cin)) * COUT + co]) : f2b(0.f);
}

// ---------------- LSTM weight: Wl[tap][cin][1024] -> wbl3[tap][kk][n'=g*256+c][32] ----------------
__global__ void cvt_wl3_k(const float* __restrict__ Wl, bf16* __restrict__ wbl3) {
    int idx = blockIdx.x * 256 + threadIdx.x;
    if (idx >= 884736) return;
    int kidx = idx & 31;
    int n    = (idx >> 5) % 768;
    int kk   = (idx >> 5) / 768 % 4;
    int tap  = idx / (32 * 768 * 4);
    int g = n >> 8, c = n & 255;
    int col = (g == 0) ? c : (g == 1 ? 512 + c : 768 + c);
    int cin = kk * 32 + kidx;
    wbl3[idx] = f2b(Wl[((long)(tap * 128 + cin)) * 1024 + col]);
}

// ---------------- FC1 weight: lw1[k=c*35+hw][j] f32 -> wfc1T8[k8g=hw*32+c8][j][8] bf16 ----------------
__global__ void cvt_fc1T8_k(const float* __restrict__ lw1, bf16* __restrict__ wfc1) {
    int t = blockIdx.x * 256 + threadIdx.x;
    if (t >= 1146880) return;
    int j   = t & 1023;
    int k8g = t >> 10;
    int hw  = k8g >> 5;
    int c8  = k8g & 31;
    float f[8];
#pragma unroll
    for (int c7 = 0; c7 < 8; c7++)
        f[c7] = lw1[((long)((c8 * 8 + c7) * 35 + hw)) * 1024 + j];
    st8(wfc1 + (long)t * 8, f);
}

// ---------------- prep: mask -> bf16 m0 (b-major), xm = bf16(x*m) (b-major) ----------------
__global__ void prep_k(const float* __restrict__ x, const int* __restrict__ mask,
                       bf16* __restrict__ m0, bf16* __restrict__ xm) {
    long idx = (long)blockIdx.x * 256 + threadIdx.x;
    if (idx >= NSITE1) return;
    float m = (mask[idx] != 0) ? 1.f : 0.f;
    m0[idx] = f2b(m);
    xm[idx * 2 + 0] = f2b(x[idx * 2 + 0] * m);
    xm[idx * 2 + 1] = f2b(x[idx * 2 + 1] * m);
}

// ---------------- transpose xm/m0 (b-major) -> xmT/m0h (hw-major), 32x32 LDS tiles ----------------
__global__ void transpose_xm(const unsigned* __restrict__ xm_u, const bf16* __restrict__ m0,
                             unsigned* __restrict__ xmT_u, bf16* __restrict__ m0h) {
    __shared__ unsigned tile[32][33];
    __shared__ bf16 mt[32][33];
    int bx = blockIdx.x % 23, by = blockIdx.x / 23;
    int hw0 = bx * 32, b0 = by * 32;
    int tid = threadIdx.x;
    int col = tid & 31, rowb = tid >> 5;
#pragma unroll
    for (int pass = 0; pass < 4; pass++) {
        int row = pass * 8 + rowb;                 // b-local
        int hw = hw0 + col;
        unsigned v = 0; bf16 m = f2b(0.f);
        if (hw < HW1) {
            long site = (long)(b0 + row) * HW1 + hw;
            v = xm_u[site]; m = m0[site];
        }
        tile[col][row] = v; mt[col][row] = m;
    }
    __syncthreads();
#pragma unroll
    for (int pass = 0; pass < 4; pass++) {
        int hwr = pass * 8 + rowb;                 // hw-local
        int hw = hw0 + hwr;
        if (hw < HW1) {
            long d = (long)hw * 2048 + b0 + col;
            xmT_u[d] = tile[hwr][col];
            m0h[d] = mt[hwr][col];
        }
    }
}

// ---------------- conv1T: 2->16, hw-uniform, fully coalesced ----------------
__global__ void conv1T(const unsigned* __restrict__ xmT_u, const float* __restrict__ W1,
                       const bf16* __restrict__ m0h, bf16* __restrict__ c1T8) {
    int bi = blockIdx.x;                 // 713*8
    int hw = bi >> 3;
    int b = (bi & 7) * 256 + threadIdx.x;
    int h = hw / IW, w = hw % IW;
    float acc[16];
#pragma unroll
    for (int i = 0; i < 16; i++) acc[i] = 0.f;
    float mk = b2f(m0h[(long)hw * 2048 + b]);
    if (mk > 0.f) {
        for (int tap = 0; tap < 9; tap++) {
            int dh = tap / 3 - 1, dw = tap % 3 - 1;
            int nh = h + dh, nw = w + dw;
            if (nh < 0 || nh >= IH || nw < 0 || nw >= IW) continue;
            int hwn = hw + dh * IW + dw;
            unsigned u = xmT_u[(long)hwn * 2048 + b];
            float i0 = __uint_as_float((u & 0xffffu) << 16);
            float i1 = __uint_as_float(u & 0xffff0000u);
            const float* wp = W1 + tap * 32;
#pragma unroll
            for (int co = 0; co < 16; co++) acc[co] += i0 * wp[co] + i1 * wp[16 + co];
        }
    }
    st8(c1T8 + ((long)hw * 2048 + b) * 8, acc);
    st8(c1T8 + (((long)HW1 + hw) * 2048 + b) * 8, acc + 8);
}

// ---------------- generic MFMA conv 3x3 SAME on T8 layouts ----------------
// A: in[k8][HW][2048][8]; B: wb[tap][kk][cout][32]; out[c8][HW][2048][8]; mask mh[hw][b].
template<int CINC, int KK, int COUT, int HW, int H, int W, int NWM, int NWN, int MT_W, int NT_W>
__global__ void __launch_bounds__(256, 2)
convT(const bf16* __restrict__ in, const bf16* __restrict__ wb,
      const bf16* __restrict__ mh, bf16* __restrict__ out) {
    constexpr int MT16 = NWM * MT_W * 16;          // 128 sites (b) per block
    __shared__ bf16 sm[MT16][COUT + 8];
    const int bi = blockIdx.x;
    constexpr int NB = 2048 / MT16;
    const int hw = bi / NB;
    const int b0 = (bi % NB) * MT16;
    const int h = hw / W, w = hw % W;
    const int tid = threadIdx.x;
    const int wv = tid >> 6, L = tid & 63, q = L >> 4, lm = L & 15;
    const int wm = wv / NWN, wn = wv % NWN;

    f4v acc[MT_W][NT_W];
#pragma unroll
    for (int i = 0; i < MT_W; i++)
#pragma unroll
        for (int j = 0; j < NT_W; j++) acc[i][j] = (f4v){0.f, 0.f, 0.f, 0.f};

    for (int tap = 0; tap < 9; tap++) {
        const int dh = tap / 3 - 1, dw = tap % 3 - 1;
        const int nh = h + dh, nw = w + dw;
        if (nh < 0 || nh >= H || nw < 0 || nw >= W) continue;   // block-uniform
        const int hwn = hw + dh * W + dw;
#pragma unroll
        for (int kk = 0; kk < KK; kk++) {
            const int k8 = (kk * 4 + q) % CINC;    // chunk-wrap for CIN<K32 (B rows zero)
            s8v a[MT_W];
#pragma unroll
            for (int i = 0; i < MT_W; i++) {
                int b = b0 + (wm * MT_W + i) * 16 + lm;
                a[i] = *(const s8v*)(in + (((long)k8 * HW + hwn) * 2048 + b) * 8);
            }
#pragma unroll
            for (int j = 0; j < NT_W; j++) {
                int co = (wn * NT_W + j) * 16 + lm;
                s8v bf = *(const s8v*)(wb + (((long)(tap * KK + kk) * COUT + co)) * 32 + q * 8);
#pragma unroll
                for (int i = 0; i < MT_W; i++)
                    acc[i][j] = __builtin_amdgcn_mfma_f32_16x16x32_bf16(a[i], bf, acc[i][j], 0, 0, 0);
            }
        }
    }
    // epilogue: mask, stage in LDS, write full lines
#pragma unroll
    for (int i = 0; i < MT_W; i++) {
#pragma unroll
        for (int r = 0; r < 4; r++) {
            int b_in = (wm * MT_W + i) * 16 + q * 4 + r;
            float mk = b2f(mh[(long)hw * 2048 + b0 + b_in]);
#pragma unroll
            for (int j = 0; j < NT_W; j++) {
                int co = (wn * NT_W + j) * 16 + lm;
                sm[b_in][co] = f2b(mk > 0.f ? acc[i][j][r] : 0.f);
            }
        }
    }
    __syncthreads();
    constexpr int TOT = MT16 * COUT / 8;
    for (int e = tid; e < TOT; e += 256) {
        int b_in = e % MT16, c8 = e / MT16;
        uint4 vv = *(const uint4*)&sm[b_in][c8 * 8];
        *(uint4*)(out + (((long)c8 * HW + hw) * 2048 + b0 + b_in) * 8) = vv;
    }
}

// ---------------- BN stats on T8 (chunk-major loop) ----------------
template<int C, int HW>
__global__ void bn_statsT8(const bf16* __restrict__ v, const bf16* __restrict__ mh,
                           float* __restrict__ sum, float* __restrict__ sumsq,
                           float* __restrict__ count) {
    __shared__ float s_sum[C], s_ss[C];
    __shared__ float s_cnt;
    int tid = threadIdx.x;
    if (tid < C) { s_sum[tid] = 0.f; s_ss[tid] = 0.f; }
    if (tid == 0) s_cnt = 0.f;
    __syncthreads();
    const long chunkN = (long)HW * 2048;
    const long stride = (long)gridDim.x * 256;
    float lc = 0.f;
    for (int k8 = 0; k8 < C / 8; k8++) {
        float ls[8], lss[8];
#pragma unroll
        for (int i = 0; i < 8; i++) { ls[i] = 0.f; lss[i] = 0.f; }
        const bf16* base = v + (long)k8 * chunkN * 8;
        for (long e = (long)blockIdx.x * 256 + tid; e < chunkN; e += stride) {
            float f[8];
            ld8(base + e * 8, f);
#pragma unroll
            for (int i = 0; i < 8; i++) { ls[i] += f[i]; lss[i] += f[i] * f[i]; }
            if (count != nullptr && k8 == 0) lc += (b2f(mh[e]) > 0.f) ? 1.f : 0.f;
        }
#pragma unroll
        for (int i = 0; i < 8; i++) {
            atomicAdd(&s_sum[k8 * 8 + i], ls[i]);
            atomicAdd(&s_ss[k8 * 8 + i], lss[i]);
        }
    }
    if (count != nullptr) atomicAdd(&s_cnt, lc);
    __syncthreads();
    if (tid < C) { atomicAdd(&sum[tid], s_sum[tid]); atomicAdd(&sumsq[tid], s_ss[tid]); }
    if (count != nullptr && tid == 0) atomicAdd(count, s_cnt);
}

template<int C>
__global__ void bn_param(const float* __restrict__ sum, const float* __restrict__ ss,
                         const float* __restrict__ count,
                         const float* __restrict__ g, const float* __restrict__ b,
                         float* __restrict__ scale, float* __restrict__ shift) {
    int c = threadIdx.x;
    if (c >= C) return;
    float n = fmaxf(count[0], 1.f);
    float mean = sum[c] / n;
    float var  = ss[c] / n - mean * mean;
    float sc = (1.f / sqrtf(var + 1e-4f)) * g[c];
    scale[c] = sc;
    shift[c] = b[c] - mean * sc;
}

// ---------------- BN apply on T8 (in-place) ----------------
template<int C, int HW>
__global__ void bn_applyT8(bf16* __restrict__ v, const bf16* __restrict__ mh,
                           const float* __restrict__ scale, const float* __restrict__ shift) {
    long i8 = (long)blockIdx.x * 256 + threadIdx.x;
    const long chunkN = (long)HW * 2048;
    if (i8 >= (C / 8) * chunkN) return;
    int k8 = (int)(i8 / chunkN);
    long s = i8 - (long)k8 * chunkN;
    int c0 = k8 * 8;
    float mk = b2f(mh[s]);
    float f[8], o[8];
    ld8(v + i8 * 8, f);
#pragma unroll
    for (int i = 0; i < 8; i++)
        o[i] = (mk > 0.f) ? fmaxf(f[i] * scale[c0 + i] + shift[c0 + i], 0.f) : 0.f;
    st8(v + i8 * 8, o);
}

// ---------------- maxpool1 + fused BN2 (T8 -> T8) ----------------
__global__ void maxpool1T(const bf16* __restrict__ c2T8, const bf16* __restrict__ m0h,
                          const float* __restrict__ scale, const float* __restrict__ shift,
                          bf16* __restrict__ p1T8, bf16* __restrict__ m1h) {
    int t = blockIdx.x * 256 + threadIdx.x;        // 4*165*2048
    if (t >= 1351680) return;
    int b = t & 2047;
    int r = t >> 11;
    int ohw = r % HW2, k8 = r / HW2;
    int oh = ohw / PW, ow = ohw % PW;
    int c0 = k8 * 8;
    float sc[8], sh[8];
#pragma unroll
    for (int i = 0; i < 8; i++) { sc[i] = scale[c0 + i]; sh[i] = shift[c0 + i]; }
    float mm = 0.f, p[8];
#pragma unroll
    for (int i = 0; i < 8; i++) p[i] = -1e30f;
    for (int kh = 0; kh < 3; kh++)
    for (int kw = 0; kw < 3; kw++) {
        int ihw = (oh * 2 + kh) * IW + (ow * 2 + kw);
        float mv = b2f(m0h[(long)ihw * 2048 + b]);
        if (mv > 0.f) {
            mm = 1.f;
            float f[8];
            ld8(c2T8 + (((long)k8 * HW1 + ihw) * 2048 + b) * 8, f);
#pragma unroll
            for (int i = 0; i < 8; i++) p[i] = fmaxf(p[i], f[i] * sc[i] + sh[i]);
        }
    }
    float o[8];
#pragma unroll
    for (int i = 0; i < 8; i++) o[i] = (mm > 0.f) ? fmaxf(p[i], 0.f) : 0.f;
    st8(p1T8 + (long)t * 8, o);
    if (k8 == 0) m1h[(long)ohw * 2048 + b] = f2b(mm);
}

// ---------------- maxpool2 + fused BN4 (T8 -> T8) ----------------
__global__ void maxpool2T(const bf16* __restrict__ c4T8, const bf16* __restrict__ m1h,
                          const float* __restrict__ scale, const float* __restrict__ shift,
                          bf16* __restrict__ p2T8, bf16* __restrict__ m2h) {
    int t = blockIdx.x * 256 + threadIdx.x;        // 16*35*2048
    if (t >= 1146880) return;
    int b = t & 2047;
    int r = t >> 11;
    int ohw = r % HW3, k8 = r / HW3;
    int oh = ohw / QW, ow = ohw % QW;
    int c0 = k8 * 8;
    float sc[8], sh[8];
#pragma unroll
    for (int i = 0; i < 8; i++) { sc[i] = scale[c0 + i]; sh[i] = shift[c0 + i]; }
    float mm = 0.f, p[8];
#pragma unroll
    for (int i = 0; i < 8; i++) p[i] = -1e30f;
    for (int kh = 0; kh < 3; kh++)
    for (int kw = 0; kw < 3; kw++) {
        int ihw = (oh * 2 + kh) * PW + (ow * 2 + kw);
        float mv = b2f(m1h[(long)ihw * 2048 + b]);
        if (mv > 0.f) {
            mm = 1.f;
            float f[8];
            ld8(c4T8 + (((long)k8 * HW2 + ihw) * 2048 + b) * 8, f);
#pragma unroll
            for (int i = 0; i < 8; i++) p[i] = fmaxf(p[i], f[i] * sc[i] + sh[i]);
        }
    }
    float o[8];
#pragma unroll
    for (int i = 0; i < 8; i++) o[i] = (mm > 0.f) ? fmaxf(p[i], 0.f) : 0.f;
    st8(p2T8 + (long)t * 8, o);
    if (k8 == 0) m2h[(long)ohw * 2048 + b] = f2b(mm);
}

// ---------------- ConvLSTM gates (R9 structure, bf16 mask) ----------------
__global__ void __launch_bounds__(256, 2)
gates_mfma(const bf16* __restrict__ p2T8, const bf16* __restrict__ wbl3,
           const float* __restrict__ bl, const bf16* __restrict__ m2h,
           bf16* __restrict__ goutT8) {
    __shared__ bf16 sm[64][136];
    const int bi = blockIdx.x;
    const int half = bi & 1;
    const int g2 = bi >> 1;
    const int hw = g2 >> 5;
    const int b0 = (g2 & 31) * 64;
    const int h = hw / QW, w = hw % QW;
    const int tid = threadIdx.x;
    const int wv = tid >> 6;
    const int L  = tid & 63;
    const int q  = L >> 4;
    const int lm = L & 15;

    f4v acc[4][2][3];
#pragma unroll
    for (int i = 0; i < 4; i++)
#pragma unroll
        for (int j = 0; j < 2; j++)
#pragma unroll
            for (int g = 0; g < 3; g++) acc[i][j][g] = (f4v){0.f, 0.f, 0.f, 0.f};

    for (int tap = 0; tap < 9; tap++) {
        const int dh = tap / 3 - 1, dw = tap % 3 - 1;
        const int nh = h + dh, nw = w + dw;
        if (nh < 0 || nh >= QH || nw < 0 || nw >= QW) continue;
        const int hwn = hw + dh * QW + dw;
#pragma unroll
        for (int kk = 0; kk < 4; kk++) {
            s8v a[4];
#pragma unroll
            for (int i = 0; i < 4; i++) {
                long idx = ((long)((kk * 4 + q) * HW3 + hwn)) * 2048 + b0 + i * 16 + lm;
                a[i] = *(const s8v*)(p2T8 + idx * 8);
            }
            const bf16* slab = wbl3 + ((long)(tap * 4 + kk)) * 768 * 32 + (long)q * 8;
#pragma unroll
            for (int j = 0; j < 2; j++) {
                int cc = half * 8 + wv * 2 + j;
#pragma unroll
                for (int g = 0; g < 3; g++) {
                    int n = g * 256 + cc * 16 + lm;
                    s8v b = *(const s8v*)(slab + (long)n * 32);
#pragma unroll
                    for (int i = 0; i < 4; i++)
                        acc[i][j][g] = __builtin_amdgcn_mfma_f32_16x16x32_bf16(a[i], b, acc[i][j][g], 0, 0, 0);
                }
            }
        }
    }
#pragma unroll
    for (int j = 0; j < 2; j++) {
        int cc = half * 8 + wv * 2 + j;
        int c = cc * 16 + lm;
        int cl = (wv * 2 + j) * 16 + lm;
        float bi_ = bl[c], bo_ = bl[512 + c], bg_ = bl[768 + c];
#pragma unroll
        for (int i = 0; i < 4; i++) {
#pragma unroll
            for (int r = 0; r < 4; r++) {
                int b_in = i * 16 + q * 4 + r;
                float m = b2f(m2h[(long)hw * 2048 + b0 + b_in]);
                float val = 0.f;
                if (m > 0.f) {
                    float iv = acc[i][j][0][r] + bi_;
                    float ov = acc[i][j][1][r] + bo_;
                    float gv = acc[i][j][2][r] + bg_;
                    float ct = sigmoidf_(iv) * tanhf(gv);
                    val = sigmoidf_(ov) * tanhf(ct);
                }
                sm[b_in][cl] = f2b(val);
            }
        }
    }
    __syncthreads();
#pragma unroll
    for (int k = 0; k < 4; k++) {
        int e = k * 256 + tid;
        int c8l = e >> 6, b_in = e & 63;
        union { uint4 u; bf16 h8[8]; } v;
#pragma unroll
        for (int i = 0; i < 8; i++) v.h8[i] = sm[b_in][c8l * 8 + i];
        long dst = ((long)(hw * 32 + half * 16 + c8l)) * 2048 + b0 + b_in;
        *(uint4*)(goutT8 + dst * 8) = v.u;
    }
}

// ---------------- FC1 via MFMA, T8 layouts ----------------
__global__ void fc1_mfma(const bf16* __restrict__ AT8, const bf16* __restrict__ WT8,
                         const float* __restrict__ lb1, bf16* __restrict__ y1) {
    const int tid = threadIdx.x;
    const int wv = tid >> 6;
    const int L  = tid & 63;
    const int q  = L >> 4, lm = L & 15;
    const int wm = wv >> 1, wn = wv & 1;
    const int bm = blockIdx.x & 31;
    const int bn = blockIdx.x >> 5;
    const int m0 = bm * 64 + wm * 32;
    const int n0 = bn * 64 + wn * 32;

    f4v acc[2][2];
#pragma unroll
    for (int i = 0; i < 2; i++)
#pragma unroll
        for (int j = 0; j < 2; j++) acc[i][j] = (f4v){0.f, 0.f, 0.f, 0.f};

#pragma unroll 2
    for (int k8 = 0; k8 < 1120; k8 += 4) {
        long ar = ((long)(k8 + q)) * 2048;
        long br = ((long)(k8 + q)) * 1024;
        s8v a0 = *(const s8v*)(AT8 + (ar + m0 + lm) * 8);
        s8v a1 = *(const s8v*)(AT8 + (ar + m0 + 16 + lm) * 8);
        s8v b0 = *(const s8v*)(WT8 + (br + n0 + lm) * 8);
        s8v b1 = *(const s8v*)(WT8 + (br + n0 + 16 + lm) * 8);
        acc[0][0] = __builtin_amdgcn_mfma_f32_16x16x32_bf16(a0, b0, acc[0][0], 0, 0, 0);
        acc[0][1] = __builtin_amdgcn_mfma_f32_16x16x32_bf16(a0, b1, acc[0][1], 0, 0, 0);
        acc[1][0] = __builtin_amdgcn_mfma_f32_16x16x32_bf16(a1, b0, acc[1][0], 0, 0, 0);
        acc[1][1] = __builtin_amdgcn_mfma_f32_16x16x32_bf16(a1, b1, acc[1][1], 0, 0, 0);
    }
#pragma unroll
    for (int i = 0; i < 2; i++) {
#pragma unroll
        for (int j = 0; j < 2; j++) {
            int nn = n0 + j * 16 + lm;
            float bias = lb1[nn];
#pragma unroll
            for (int r = 0; r < 4; r++) {
                int mm = m0 + i * 16 + q * 4 + r;
                y1[(long)mm * 1024 + nn] = f2b(fmaxf(acc[i][j][r] + bias, 0.f));
            }
        }
    }
}

// ---------------- FC2 ----------------
__global__ void fc2_k(const bf16* __restrict__ y1, const float* __restrict__ lw2,
                      const float* __restrict__ lb2, float* __restrict__ out) {
    long idx = (long)blockIdx.x * 256 + threadIdx.x;
    long total = (long)BB * 420;
    if (idx >= total) return;
    int j = (int)(idx % 420); long b = idx / 420;
    float acc = lb2[j];
    const bf16* yr = y1 + b * 1024;
    for (int k8 = 0; k8 < 1024; k8 += 8) {
        float f[8];
        ld8(yr + k8, f);
#pragma unroll
        for (int i = 0; i < 8; i++) acc += f[i] * lw2[(long)(k8 + i) * 420 + j];
    }
    out[idx] = acc;
}

// ---------------- launch ----------------
extern "C" void kernel_launch(void* const* d_in, const int* in_sizes, int n_in,
                              void* d_out, int out_size, void* d_ws, size_t ws_size,
                              hipStream_t stream) {
    const float* x    = (const float*)d_in[0];
    const int*   mask = (const int*)d_in[1];
    const float* W1 = (const float*)d_in[2];
    const float* g1 = (const float*)d_in[3];
    const float* b1 = (const float*)d_in[4];
    const float* W2 = (const float*)d_in[5];
    const float* g2 = (const float*)d_in[6];
    const float* b2 = (const float*)d_in[7];
    const float* W3 = (const float*)d_in[8];
    const float* g3 = (const float*)d_in[9];
    const float* b3 = (const float*)d_in[10];
    const float* W4 = (const float*)d_in[11];
    const float* g4 = (const float*)d_in[12];
    const float* b4 = (const float*)d_in[13];
    const float* Wl = (const float*)d_in[14];
    const float* bl = (const float*)d_in[15];
    const float* lw1 = (const float*)d_in[16];
    const float* lb1 = (const float*)d_in[17];
    const float* lw2 = (const float*)d_in[18];
    const float* lb2 = (const float*)d_in[19];
    float* out = (float*)d_out;

    float* ws = (float*)d_ws;
    bf16* bfb = (bf16*)(ws + 4096);
    bf16* m0   = bfb + MOFF_M0;
    bf16* m0h  = bfb + MOFF_M0H;
    bf16* m1h  = bfb + MOFF_M1H;
    bf16* m2h  = bfb + MOFF_M2H;
    bf16* A    = bfb + AOFF;
    bf16* B    = bfb + BOFF;

    bf16* c1T8   = A;                         // [2][713][2048][8]
    unsigned* xmT_u = (unsigned*)(A + A_XMT); // [713][2048] uint (2 bf16)
    bf16* wb2    = A + A_WB2;
    bf16* wb3    = A + A_WB3;
    bf16* p1T8   = A;                         // [4][165][2048][8]
    bf16* c4T8   = A;                         // [16][165][2048][8]
    bf16* goutT8 = A;                         // [1120][2048][8]
    bf16* wbl3   = A + A_WBL;
    bf16* xm     = B;                         // [NSITE1][2]
    unsigned* xm_u = (unsigned*)B;
    bf16* c2T8   = B;                         // [4][713][2048][8]
    bf16* c3T8   = B;                         // [8][165][2048][8]
    bf16* wb4    = B + B_WB4;
    bf16* wfc1   = B + B_WFC1;
    bf16* p2T8   = B;                         // [16][35][2048][8]
    bf16* y1     = B;                         // [2048][1024]

    hipMemsetAsync(ws, 0, 8192, stream);   // BN stat accumulators

    prep_k<<<(int)(NSITE1 / 256), 256, 0, stream>>>(x, mask, m0, xm);
    cvt_wsplit_k<<<(9216 + 255) / 256, 256, 0, stream>>>(W2, wb2, 16, 32, 1, 9216);
    cvt_wsplit_k<<<(18432 + 255) / 256, 256, 0, stream>>>(W3, wb3, 32, 64, 1, 18432);

    transpose_xm<<<23 * 64, 256, 0, stream>>>(xm_u, m0, xmT_u, m0h);

    conv1T<<<HW1 * 8, 256, 0, stream>>>(xmT_u, W1, m0h, c1T8);
    bn_statsT8<16, HW1><<<1280, 256, 0, stream>>>(c1T8, m0h, ws + OFF_S1, ws + OFF_Q1, ws + OFF_N1);
    bn_param<16><<<1, 16, 0, stream>>>(ws + OFF_S1, ws + OFF_Q1, ws + OFF_N1, g1, b1, ws + OFF_SC1, ws + OFF_SH1);
    bn_applyT8<16, HW1><<<(int)(2L * HW1 * 2048 / 256), 256, 0, stream>>>(c1T8, m0h, ws + OFF_SC1, ws + OFF_SH1);

    // conv2: 16->32 (CINC=2, chunk-wrap + zero-padded B rows)
    convT<2, 1, 32, HW1, IH, IW, 2, 2, 4, 1><<<HW1 * 16, 256, 0, stream>>>(c1T8, wb2, m0h, c2T8);
    bn_statsT8<32, HW1><<<1280, 256, 0, stream>>>(c2T8, m0h, ws + OFF_S2, ws + OFF_Q2, nullptr);
    bn_param<32><<<1, 32, 0, stream>>>(ws + OFF_S2, ws + OFF_Q2, ws + OFF_N1, g2, b2, ws + OFF_SC2, ws + OFF_SH2);

    maxpool1T<<<(1351680 + 255) / 256, 256, 0, stream>>>(c2T8, m0h, ws + OFF_SC2, ws + OFF_SH2, p1T8, m1h);

    // c2T8 dead: stash wb4, wfc1 in B slack
    cvt_wsplit_k<<<(73728 + 255) / 256, 256, 0, stream>>>(W4, wb4, 64, 128, 2, 73728);
    cvt_fc1T8_k<<<(1146880 + 255) / 256, 256, 0, stream>>>(lw1, wfc1);

    // conv3: 32->64
    convT<4, 1, 64, HW2, PH, PW, 2, 2, 4, 2><<<HW2 * 16, 256, 0, stream>>>(p1T8, wb3, m1h, c3T8);
    bn_statsT8<64, HW2><<<1280, 256, 0, stream>>>(c3T8, m1h, ws + OFF_S3, ws + OFF_Q3, ws + OFF_N2);
    bn_param<64><<<1, 64, 0, stream>>>(ws + OFF_S3, ws + OFF_Q3, ws + OFF_N2, g3, b3, ws + OFF_SC3, ws + OFF_SH3);
    bn_applyT8<64, HW2><<<(int)(8L * HW2 * 2048 / 256), 256, 0, stream>>>(c3T8, m1h, ws + OFF_SC3, ws + OFF_SH3);

    // conv4: 64->128
    convT<8, 2, 128, HW2, PH, PW, 2, 2, 4, 4><<<HW2 * 16, 256, 0, stream>>>(c3T8, wb4, m1h, c4T8);
    bn_statsT8<128, HW2><<<1280, 256, 0, stream>>>(c4T8, m1h, ws + OFF_S4, ws + OFF_Q4, nullptr);
    bn_param<128><<<1, 128, 0, stream>>>(ws + OFF_S4, ws + OFF_Q4, ws + OFF_N2, g4, b4, ws + OFF_SC4, ws + OFF_SH4);

    maxpool2T<<<(1146880 + 255) / 256, 256, 0, stream>>>(c4T8, m1h, ws + OFF_SC4, ws + OFF_SH4, p2T8, m2h);

    // c4T8 dead: convert wbl3
    cvt_wl3_k<<<(884736 + 255) / 256, 256, 0, stream>>>(Wl, wbl3);

    gates_mfma<<<2240, 256, 0, stream>>>(p2T8, wbl3, bl, m2h, goutT8);

    fc1_mfma<<<512, 256, 0, stream>>>(goutT8, wfc1, lb1, y1);

    fc2_k<<<(int)((BB * 420L + 255) / 256), 256, 0, stream>>>(y1, lw2, lb2, out);
}